// Round 3
// baseline (664.333 us; speedup 1.0000x reference)
//
#include <hip/hip_runtime.h>
#include <hip/hip_bf16.h>

typedef float f4 __attribute__((ext_vector_type(4)));
typedef short s8v __attribute__((ext_vector_type(8)));      // 8 bf16 (MFMA frag)
typedef unsigned short us4 __attribute__((ext_vector_type(4)));
typedef unsigned short us8 __attribute__((ext_vector_type(8)));

#define AP 40  // LDS row pad: 40 ushorts = 80 B = 20 banks -> 2-way (free)

// ---------------------------------------------------------------------------
// Stem: 512x512x3 --7x7 s2 pad2--> 256x256x64, ReLU. (fp32, small)
// ---------------------------------------------------------------------------
__global__ __launch_bounds__(256) void stem_kernel(
    const float* __restrict__ in, const float* __restrict__ w,
    float* __restrict__ out)
{
  __shared__ float in_lds[37 * 37 * 3];
  __shared__ float w_lds[7 * 7 * 3 * 64];
  const int tid = threadIdx.x;
  const int ty0 = (blockIdx.x >> 4) * 16;
  const int tx0 = (blockIdx.x & 15) * 16;

  for (int idx = tid; idx < 9408; idx += 256) w_lds[idx] = w[idx];
  for (int idx = tid; idx < 4107; idx += 256) {
    int ci = idx % 3;
    int rem = idx / 3;
    int ix = rem % 37, iy = rem / 37;
    int gy = ty0 * 2 - 2 + iy, gx = tx0 * 2 - 2 + ix;
    float v = 0.f;
    if ((unsigned)gy < 512u && (unsigned)gx < 512u)
      v = in[(gy * 512 + gx) * 3 + ci];
    in_lds[idx] = v;
  }
  __syncthreads();

  const int co = (tid & 15) * 4;
  const int py = tid >> 4;
  f4 acc[16];
#pragma unroll
  for (int px = 0; px < 16; ++px) acc[px] = (f4)0.f;

  for (int ky = 0; ky < 7; ++ky)
    for (int kx = 0; kx < 7; ++kx)
#pragma unroll
      for (int ci = 0; ci < 3; ++ci) {
        f4 wv = *(const f4*)&w_lds[(((ky * 7 + kx) * 3) + ci) * 64 + co];
        const float* ip = &in_lds[((2 * py + ky) * 37 + kx) * 3 + ci];
#pragma unroll
        for (int px = 0; px < 16; ++px) {
          float iv = ip[px * 6];
          acc[px] += iv * wv;
        }
      }

#pragma unroll
  for (int px = 0; px < 16; ++px) {
    int oy = ty0 + py, ox = tx0 + px;
    f4 o = acc[px];
#pragma unroll
    for (int c = 0; c < 4; ++c) o[c] = fmaxf(o[c], 0.f);
    *(f4*)&out[(oy * 256 + ox) * 64 + co] = o;
  }
}

// ---------------------------------------------------------------------------
// Weight prep: fp32 [tap][ci][co] -> 3-term bf16 split, TRANSPOSED to
// [L][tap][co][ci] (ushort).
// ---------------------------------------------------------------------------
__global__ __launch_bounds__(256) void wsplit_kernel(
    const float* __restrict__ w, unsigned short* __restrict__ wt,
    int C_in, int C_out, int taps)
{
  __shared__ float t[64][68];
  const int tid = threadIdx.x;
  const int tap = blockIdx.z;
  const int ci0 = blockIdx.x * 64;
  const int co0 = blockIdx.y * 64;
  const size_t lstride = (size_t)taps * C_in * C_out;

#pragma unroll
  for (int q = 0; q < 4; ++q) {
    int f = q * 256 + tid;
    int r = f >> 4, c = f & 15;  // r = ci row, c = co f4-col
    f4 v = *(const f4*)&w[((size_t)(tap * C_in + ci0 + r)) * C_out + co0 + c * 4];
    *(f4*)&t[r][c * 4] = v;
  }
  __syncthreads();

#pragma unroll
  for (int q = 0; q < 4; ++q) {
    int f = q * 256 + tid;
    int r = f >> 4, c = f & 15;  // r = co row, c = ci f4-col
    us4 h, m, l;
#pragma unroll
    for (int u = 0; u < 4; ++u) {
      float s = t[c * 4 + u][r];
      unsigned int ub = __float_as_uint(s);
      unsigned short hh = (unsigned short)(ub >> 16);
      float r1 = s - __uint_as_float((unsigned int)hh << 16);
      unsigned short mm = (unsigned short)(__float_as_uint(r1) >> 16);
      float r2 = r1 - __uint_as_float((unsigned int)mm << 16);
      unsigned short ll = (unsigned short)(__float_as_uint(r2) >> 16);
      h[u] = hh; m[u] = mm; l[u] = ll;
    }
    size_t base = ((size_t)tap * C_out + co0 + r) * C_in + ci0 + c * 4;
    *(us4*)&wt[base] = h;
    *(us4*)&wt[lstride + base] = m;
    *(us4*)&wt[2 * lstride + base] = l;
  }
}

// ---------------------------------------------------------------------------
// 3x3 conv via MFMA (16x16x32 bf16) with exact 3-term split (6 products).
// Tile 128 pix x 128 co, 4 waves, chunk K=32. LDS rows padded to AP=40.
// R10: register-pipelined staging + bijective XCD swizzle (validated).
// ---------------------------------------------------------------------------
__global__ __launch_bounds__(256, 2) void conv_mfma(
    const float* __restrict__ in, const unsigned short* __restrict__ wt,
    float* __restrict__ pout,
    int H_in, int W_in, int C_in, int wshift, int C_out,
    int stride, int pad, int ci_per_z, int npix, int relu)
{
  __shared__ __align__(16) unsigned short At[3][128][AP];
  __shared__ __align__(16) unsigned short Bt[3][128][AP];  // [L][co][k]
  const int tid = threadIdx.x;

  // XCD-aware bijective swizzle: HW round-robins flat block id across 8 XCDs;
  // remap so XCD x gets contiguous work [x*nwg/8, (x+1)*nwg/8).
  const int nwg = gridDim.x * gridDim.y * gridDim.z;
  const int hwid = blockIdx.x + gridDim.x * (blockIdx.y + gridDim.y * blockIdx.z);
  const int wid = ((nwg & 7) == 0) ? (hwid & 7) * (nwg >> 3) + (hwid >> 3) : hwid;
  const int bx = wid % gridDim.x;
  const int brem = wid / gridDim.x;
  const int by = brem % gridDim.y;
  const int bz = brem / gridDim.y;

  const int pix_base = bx * 128;
  const int co_base = by * 128;
  const int ci_z0 = bz * ci_per_z;
  const int wmask = (1 << wshift) - 1;
  const size_t lstride = (size_t)9 * C_in * C_out;

  const int lane = tid & 63, wv = tid >> 6;
  const int pixhalf = (wv >> 1) * 64, cohalf = (wv & 1) * 64;
  const int fm = lane & 15, fq = lane >> 4;

  int a_pix[4], a_c4[4], a_ys[4], a_xs[4];
#pragma unroll
  for (int q = 0; q < 4; ++q) {
    int f = q * 256 + tid;
    a_pix[q] = f >> 3; a_c4[q] = f & 7;
    int p = pix_base + a_pix[q];
    a_ys[q] = (p >> wshift) * stride - pad;
    a_xs[q] = (p & wmask) * stride - pad;
  }
  int b_col[2], b_seg[2];
#pragma unroll
  for (int q = 0; q < 2; ++q) {
    int f = q * 256 + tid;
    b_col[q] = f >> 2; b_seg[q] = (f & 3) * 8;
  }

  const int nc = ci_per_z >> 5;       // chunks per tap: 1 or 2
  const int ncsh = nc >> 1;           // log2(nc): 0 or 1
  const int nchunks = 9 * nc;

  f4 areg[4];
  us8 breg[6];
  auto issue_loads = [&](int c) {
    int tap = c >> ncsh;
    int ci = ci_z0 + (c & (nc - 1)) * 32;
    int ky = tap / 3, kx = tap - ky * 3;
#pragma unroll
    for (int q = 0; q < 4; ++q) {
      int iy = a_ys[q] + ky, ix = a_xs[q] + kx;
      bool v = ((unsigned)iy < (unsigned)H_in) & ((unsigned)ix < (unsigned)W_in);
      const float* p = in + (size_t)(iy * W_in + ix) * C_in + ci + a_c4[q] * 4;
      areg[q] = v ? *(const f4*)p : (f4)0.f;
    }
    const unsigned short* bb =
        wt + (size_t)tap * C_out * C_in + (size_t)co_base * C_in + ci;
#pragma unroll
    for (int L = 0; L < 3; ++L)
#pragma unroll
      for (int q = 0; q < 2; ++q)
        breg[L * 2 + q] = *(const us8*)(bb + (size_t)L * lstride +
                                        (size_t)b_col[q] * C_in + b_seg[q]);
  };

  us4 ah[4], am[4], al[4];
  auto convert = [&]() {
#pragma unroll
    for (int q = 0; q < 4; ++q) {
      f4 s4 = areg[q];
      us4 h, m, l;
#pragma unroll
      for (int u = 0; u < 4; ++u) {
        float s = s4[u];
        unsigned int ub = __float_as_uint(s);
        unsigned short hh = (unsigned short)(ub >> 16);
        float r1 = s - __uint_as_float((unsigned int)hh << 16);
        unsigned short mm = (unsigned short)(__float_as_uint(r1) >> 16);
        float r2 = r1 - __uint_as_float((unsigned int)mm << 16);
        unsigned short ll = (unsigned short)(__float_as_uint(r2) >> 16);
        h[u] = hh; m[u] = mm; l[u] = ll;
      }
      ah[q] = h; am[q] = m; al[q] = l;
    }
  };

  f4 acc[4][4];
#pragma unroll
  for (int i = 0; i < 4; ++i)
#pragma unroll
    for (int j = 0; j < 4; ++j) acc[i][j] = (f4)0.f;

  issue_loads(0);
  convert();

  for (int c = 0; c < nchunks; ++c) {
    __syncthreads();
#pragma unroll
    for (int q = 0; q < 4; ++q) {
      *(us4*)&At[0][a_pix[q]][a_c4[q] * 4] = ah[q];
      *(us4*)&At[1][a_pix[q]][a_c4[q] * 4] = am[q];
      *(us4*)&At[2][a_pix[q]][a_c4[q] * 4] = al[q];
    }
#pragma unroll
    for (int L = 0; L < 3; ++L)
#pragma unroll
      for (int q = 0; q < 2; ++q)
        *(us8*)&Bt[L][b_col[q]][b_seg[q]] = breg[L * 2 + q];
    __syncthreads();

    const bool more = (c + 1 < nchunks);
    if (more) issue_loads(c + 1);  // latency hidden under the MFMAs below

    s8v Bh[4], Bm[4], Bl[4];
#pragma unroll
    for (int j = 0; j < 4; ++j) {
      Bh[j] = *(const s8v*)&Bt[0][cohalf + j * 16 + fm][fq * 8];
      Bm[j] = *(const s8v*)&Bt[1][cohalf + j * 16 + fm][fq * 8];
      Bl[j] = *(const s8v*)&Bt[2][cohalf + j * 16 + fm][fq * 8];
    }
    {
      s8v Ah[4];
#pragma unroll
      for (int i = 0; i < 4; ++i)
        Ah[i] = *(const s8v*)&At[0][pixhalf + i * 16 + fm][fq * 8];
#pragma unroll
      for (int i = 0; i < 4; ++i)
#pragma unroll
        for (int j = 0; j < 4; ++j) {
          acc[i][j] = __builtin_amdgcn_mfma_f32_16x16x32_bf16(Ah[i], Bh[j], acc[i][j], 0, 0, 0);
          acc[i][j] = __builtin_amdgcn_mfma_f32_16x16x32_bf16(Ah[i], Bm[j], acc[i][j], 0, 0, 0);
          acc[i][j] = __builtin_amdgcn_mfma_f32_16x16x32_bf16(Ah[i], Bl[j], acc[i][j], 0, 0, 0);
        }
    }
    {
      s8v Am[4];
#pragma unroll
      for (int i = 0; i < 4; ++i)
        Am[i] = *(const s8v*)&At[1][pixhalf + i * 16 + fm][fq * 8];
#pragma unroll
      for (int i = 0; i < 4; ++i)
#pragma unroll
        for (int j = 0; j < 4; ++j) {
          acc[i][j] = __builtin_amdgcn_mfma_f32_16x16x32_bf16(Am[i], Bh[j], acc[i][j], 0, 0, 0);
          acc[i][j] = __builtin_amdgcn_mfma_f32_16x16x32_bf16(Am[i], Bm[j], acc[i][j], 0, 0, 0);
        }
    }
    {
      s8v Al[4];
#pragma unroll
      for (int i = 0; i < 4; ++i)
        Al[i] = *(const s8v*)&At[2][pixhalf + i * 16 + fm][fq * 8];
#pragma unroll
      for (int i = 0; i < 4; ++i)
#pragma unroll
        for (int j = 0; j < 4; ++j)
          acc[i][j] = __builtin_amdgcn_mfma_f32_16x16x32_bf16(Al[i], Bh[j], acc[i][j], 0, 0, 0);
    }

    if (more) convert();  // fp32->3xbf16 split of chunk c+1, in MFMA shadow
  }

  float* dst = pout + (size_t)bz * npix * C_out;
#pragma unroll
  for (int i = 0; i < 4; ++i) {
#pragma unroll
    for (int j = 0; j < 4; ++j) {
#pragma unroll
      for (int r = 0; r < 4; ++r) {
        int p = pix_base + pixhalf + i * 16 + fq * 4 + r;
        int co = co_base + cohalf + j * 16 + fm;
        float v = acc[i][j][r];
        if (relu) v = fmaxf(v, 0.f);
        dst[(size_t)p * C_out + co] = v;
      }
    }
  }
}

// ---------------------------------------------------------------------------
// Sum Z partial slices (f4-vectorized) + optional ReLU.
// ---------------------------------------------------------------------------
__global__ __launch_bounds__(256) void reduce_relu_kernel(
    const float* __restrict__ p, float* __restrict__ out, int n4, int Z, int relu)
{
  int idx = blockIdx.x * 256 + threadIdx.x;
  if (idx >= n4) return;
  const f4* pv = (const f4*)p;
  f4 s = pv[idx];
  for (int z = 1; z < Z; ++z) s += pv[(size_t)z * n4 + idx];
  if (relu) {
#pragma unroll
    for (int c = 0; c < 4; ++c) s[c] = fmaxf(s[c], 0.f);
  }
  ((f4*)out)[idx] = s;
}

// ---------------------------------------------------------------------------
// 1x1-conv GEMM tile: 64 pix x 64 co, 256 thr, 4 pix x 4 co per thread.
// ---------------------------------------------------------------------------
__global__ __launch_bounds__(256) void gemm64(
    const float* __restrict__ in, const float* __restrict__ w,
    float* __restrict__ pout, int C_in, int C_out, int ci_per_z, int npix)
{
  __shared__ __align__(16) float As2[32][68];
  __shared__ __align__(16) float Bs[32][64];
  const int tid = threadIdx.x;
  const int pix_base = blockIdx.x * 64;
  const int co_base = blockIdx.y * 64;
  const int ci_z0 = blockIdx.z * ci_per_z;
  const int tx = tid & 15, ty = tid >> 4;

  int ga_pix[2], ga_c4[2];
#pragma unroll
  for (int q = 0; q < 2; ++q) {
    int f = q * 256 + tid;
    ga_pix[q] = f >> 3; ga_c4[q] = f & 7;
  }
  int gb_row[2], gb_c4[2];
#pragma unroll
  for (int q = 0; q < 2; ++q) {
    int f = q * 256 + tid;
    gb_row[q] = f >> 4; gb_c4[q] = f & 15;
  }

  f4 acc[4];
#pragma unroll
  for (int i = 0; i < 4; ++i) acc[i] = (f4)0.f;

  for (int ci = ci_z0; ci < ci_z0 + ci_per_z; ci += 32) {
    __syncthreads();
#pragma unroll
    for (int q = 0; q < 2; ++q) {
      f4 av = *(const f4*)&in[(size_t)(pix_base + ga_pix[q]) * C_in + ci + ga_c4[q] * 4];
#pragma unroll
      for (int u = 0; u < 4; ++u) As2[ga_c4[q] * 4 + u][ga_pix[q]] = av[u];
    }
#pragma unroll
    for (int q = 0; q < 2; ++q) {
      *(f4*)&Bs[gb_row[q]][gb_c4[q] * 4] =
          *(const f4*)&w[(size_t)(ci + gb_row[q]) * C_out + co_base + gb_c4[q] * 4];
    }
    __syncthreads();
#pragma unroll
    for (int kk = 0; kk < 32; ++kk) {
      f4 a = *(const f4*)&As2[kk][ty * 4];
      f4 b = *(const f4*)&Bs[kk][tx * 4];
#pragma unroll
      for (int i = 0; i < 4; ++i) acc[i] += a[i] * b;
    }
  }

  float* dst = pout + (size_t)blockIdx.z * npix * C_out;
#pragma unroll
  for (int i = 0; i < 4; ++i)
    *(f4*)&dst[(size_t)(pix_base + ty * 4 + i) * C_out + co_base + tx * 4] = acc[i];
}

// ---------------------------------------------------------------------------
// Sum Z partial slices + optional fused nearest-up2 residual (C_out=256).
// ---------------------------------------------------------------------------
__global__ __launch_bounds__(256) void reduce_up2_kernel(
    const float* __restrict__ p, const float* __restrict__ res,
    float* __restrict__ out, int n4, int Z, int wshift)
{
  int idx = blockIdx.x * 256 + threadIdx.x;
  if (idx >= n4) return;
  const f4* pv = (const f4*)p;
  f4 s = pv[idx];
  for (int z = 1; z < Z; ++z) s += pv[(size_t)z * n4 + idx];
  if (res) {
    int pix = idx >> 6, c4 = idx & 63;
    int oy = pix >> wshift, ox = pix & ((1 << wshift) - 1);
    int rp = ((oy >> 1) << (wshift - 1)) + (ox >> 1);
    s += ((const f4*)res)[rp * 64 + c4];
  }
  ((f4*)out)[idx] = s;
}

// ---------------------------------------------------------------------------
// obj head (1x1, 256->1) + sigmoid. 4 threads/pixel, quad shuffle-reduce.
// ---------------------------------------------------------------------------
__global__ __launch_bounds__(256) void obj_sigmoid_kernel(
    const float* __restrict__ t, const float* __restrict__ wobj,
    float* __restrict__ scores)
{
  __shared__ float wl[256];
  const int tid = threadIdx.x;
  wl[tid] = wobj[tid];
  __syncthreads();
  const int pix = blockIdx.x * 64 + (tid >> 2);
  const int c0 = (tid & 3) * 64;
  float acc = 0.f;
#pragma unroll
  for (int k = 0; k < 16; ++k) {
    f4 tv = *(const f4*)&t[(size_t)pix * 256 + c0 + k * 4];
    const float* wp = &wl[c0 + k * 4];
    acc += tv[0] * wp[0] + tv[1] * wp[1] + tv[2] * wp[2] + tv[3] * wp[3];
  }
  acc += __shfl_xor(acc, 1);
  acc += __shfl_xor(acc, 2);
  if ((tid & 3) == 0) scores[pix] = 1.f / (1.f + expf(-acc));
}

// ---------------------------------------------------------------------------
// NMS via sort + scan-accept.
// R11: register-resident bitonic sort. Element e = tid*4+v lives in kr[v] of
// thread tid. Same comparator network as before -> bit-identical output.
//  - j=1,2   : in-thread compares (no LDS, no sync)          [23 stages]
//  - j=4..128: partner lane = tid^(j/4) < 64 -> __shfl_xor    [45 stages]
//  - j>=256  : cross-wave via LDS (write, bar, read, bar)     [10 stages]
// LDS round-trips drop 78 -> 10; the rest runs at VALU/shuffle throughput.
// ---------------------------------------------------------------------------
__global__ __launch_bounds__(1024) void nms_kernel(
    const float* __restrict__ scores, float* __restrict__ out)
{
  __shared__ unsigned long long keys[4096];  // 32 KB
  __shared__ float acc_lds[100 * 8];         // accepted: b0,b1,b2,b3,area
  const int tid = threadIdx.x;
  const float inv63 = 1.0f / 63.0f;

  if (tid < 125) ((f4*)out)[tid] = (f4)0.f;

  unsigned long long kr[4];
  {
    f4 sv = ((const f4*)scores)[tid];
#pragma unroll
    for (int v = 0; v < 4; ++v) {
      unsigned int bits = __float_as_uint(sv[v]);  // in [0, 0x3F800000]
      kr[v] = ((unsigned long long)(0x40000000u - bits) << 16) |
              (unsigned long long)(tid * 4 + v);
    }
  }

  for (int k = 2; k <= 4096; k <<= 1) {
    // --- cross-wave stages (j >= 256) via LDS ---
    for (int j = k >> 1; j >= 256; j >>= 1) {
      *(ulonglong2*)&keys[tid * 4] = ulonglong2{kr[0], kr[1]};
      *(ulonglong2*)&keys[tid * 4 + 2] = ulonglong2{kr[2], kr[3]};
      __syncthreads();
      ulonglong2 p0 = *(const ulonglong2*)&keys[(tid * 4) ^ j];
      ulonglong2 p1 = *(const ulonglong2*)&keys[((tid * 4) ^ j) + 2];
      unsigned long long pb[4] = {p0.x, p0.y, p1.x, p1.y};
#pragma unroll
      for (int v = 0; v < 4; ++v) {
        int e = tid * 4 + v;
        bool up = ((e & k) == 0);
        bool lower = ((e & j) == 0);
        bool keep_min = (lower == up);
        unsigned long long a = kr[v], b = pb[v];
        unsigned long long mn = a < b ? a : b;
        unsigned long long mx = a < b ? b : a;
        kr[v] = keep_min ? mn : mx;
      }
      __syncthreads();  // protect this stage's reads from next stage's writes
    }
    // --- intra-wave stages (j = 4..128) via shfl_xor ---
    {
      int js = (k >> 1) < 128 ? (k >> 1) : 128;
      for (int j = js; j >= 4; j >>= 1) {
        int lm = j >> 2;  // lane xor mask (1..32)
        bool lower = ((tid & lm) == 0);
        bool up = ((tid & (k >> 2)) == 0);  // k >= 8 here
        bool keep_min = (lower == up);
#pragma unroll
        for (int v = 0; v < 4; ++v) {
          unsigned long long b = __shfl_xor(kr[v], lm);
          unsigned long long a = kr[v];
          unsigned long long mn = a < b ? a : b;
          unsigned long long mx = a < b ? b : a;
          kr[v] = keep_min ? mn : mx;
        }
      }
    }
    // --- in-thread stage j = 2 (pairs (v0,v2),(v1,v3)) ---
    if (k >= 4) {
#pragma unroll
      for (int v = 0; v < 2; ++v) {
        bool up = (((tid * 4 + v) & k) == 0);
        unsigned long long a = kr[v], b = kr[v + 2];
        if ((a > b) == up) { kr[v] = b; kr[v + 2] = a; }
      }
    }
    // --- in-thread stage j = 1 (pairs (v0,v1),(v2,v3)) ---
    {
#pragma unroll
      for (int v = 0; v < 4; v += 2) {
        bool up = (((tid * 4 + v) & k) == 0);
        unsigned long long a = kr[v], b = kr[v + 1];
        if ((a > b) == up) { kr[v] = b; kr[v + 1] = a; }
      }
    }
  }

  // publish sorted keys for the greedy phase
  *(ulonglong2*)&keys[tid * 4] = ulonglong2{kr[0], kr[1]};
  *(ulonglong2*)&keys[tid * 4 + 2] = ulonglong2{kr[2], kr[3]};
  __syncthreads();

  if (tid >= 64) return;
  const int lane = tid;

  int n = 0;
  for (int b = 0; b < 64 && n < 100; ++b) {
    unsigned long long kk = keys[b * 64 + lane];
    int idx = (int)(kk & 0xFFFF);
    float sc = __uint_as_float(0x40000000u - (unsigned int)(kk >> 16));
    int si = idx >> 6, sj = idx & 63;
    float y = sj * inv63, x = si * inv63;
    float c0 = fmaxf(y - 0.05f, 0.f), c1 = fmaxf(x - 0.05f, 0.f);
    float c2 = fminf(y + 0.05f, 1.f), c3 = fminf(x + 0.05f, 1.f);
    float carea = (c2 - c0) * (c3 - c1);

    bool sup = false;
    for (int a = 0; a < n; ++a) {
      f4 ab = *(const f4*)&acc_lds[a * 8];
      float aarea = acc_lds[a * 8 + 4];
      float yy1 = fmaxf(ab[0], c0), xx1 = fmaxf(ab[1], c1);
      float yy2 = fminf(ab[2], c2), xx2 = fminf(ab[3], c3);
      float inter = fmaxf(yy2 - yy1, 0.f) * fmaxf(xx2 - xx1, 0.f);
      float iou = inter / (aarea + carea - inter + 1e-9f);
      sup = sup || (iou > 0.5f);
    }

    unsigned long long m = __ballot(!sup);
    while (m != 0 && n < 100) {
      int u = __builtin_ctzll(m);
      float b0 = __shfl(c0, u), b1 = __shfl(c1, u);
      float b2 = __shfl(c2, u), b3 = __shfl(c3, u);
      float ba = __shfl(carea, u);
      if (lane == u) {
        acc_lds[n * 8 + 0] = c0; acc_lds[n * 8 + 1] = c1;
        acc_lds[n * 8 + 2] = c2; acc_lds[n * 8 + 3] = c3;
        acc_lds[n * 8 + 4] = carea;
        out[n * 4 + 0] = c0; out[n * 4 + 1] = c1;
        out[n * 4 + 2] = c2; out[n * 4 + 3] = c3;
        out[400 + n] = sc;
        sup = true;
      }
      n++;
      if (lane > u && !sup) {
        float yy1 = fmaxf(b0, c0), xx1 = fmaxf(b1, c1);
        float yy2 = fminf(b2, c2), xx2 = fminf(b3, c3);
        float inter = fmaxf(yy2 - yy1, 0.f) * fmaxf(xx2 - xx1, 0.f);
        float iou = inter / (ba + carea - inter + 1e-9f);
        if (iou > 0.5f) sup = true;
      }
      m = __ballot(!sup);
    }
    __threadfence_block();
  }
}

// ---------------------------------------------------------------------------
extern "C" void kernel_launch(void* const* d_in, const int* in_sizes, int n_in,
                              void* d_out, int out_size, void* d_ws, size_t ws_size,
                              hipStream_t stream) {
  const float* x      = (const float*)d_in[0];
  const float* w_stem = (const float*)d_in[1];
  const float* w_c2   = (const float*)d_in[2];
  const float* w_c3   = (const float*)d_in[3];
  const float* w_c4   = (const float*)d_in[4];
  const float* w_c5   = (const float*)d_in[5];
  const float* l3     = (const float*)d_in[6];
  const float* l4     = (const float*)d_in[7];
  const float* l5     = (const float*)d_in[8];
  const float* o3w    = (const float*)d_in[9];
  const float* w_rpn  = (const float*)d_in[12];
  const float* w_obj  = (const float*)d_in[13];
  float* out = (float*)d_out;
  float* ws = (float*)d_ws;

  float* S   = ws;              // 4,194,304 floats (partial scratch for c4/c5/o3/rpn)
  float* C2  = S   + 4194304;   // 4,194,304
  float* C3  = C2  + 4194304;   // 2,097,152
  float* C4  = C3  + 2097152;   // 1,048,576
  float* C5  = C4  + 1048576;   //   524,288
  float* P5  = C5  + 524288;    //    65,536
  float* P4  = P5  + 65536;     //   262,144
  float* P3P = P4  + 262144;    // 1,048,576
  float* P3  = P3P + 1048576;   // 1,048,576
  float* T   = P3  + 1048576;   // 1,048,576
  float* SC  = T   + 1048576;   //     4,096
  unsigned short* WT = (unsigned short*)(SC + 4096);  // 113.25 MB weight split
  // PZ: 33.5 MB partial scratch for c2/c3, carved at WT+60 MB. Safe: c2/c3
  // weight splits are 1.7/7.1 MB (< 60 MB); c4's 28.3 MB < 60 MB; c5's full
  // 113 MB rewrite happens only after c3 is consumed (stream-serial).
  float* PZ = (float*)(WT + 31457280);

  // backbone
  stem_kernel<<<256, 256, 0, stream>>>(x, w_stem, S);

  wsplit_kernel<<<dim3(1, 4, 9), 256, 0, stream>>>(w_c2, WT, 64, 256, 9);
  conv_mfma<<<dim3(128, 2, 2), 256, 0, stream>>>(   // Z=2: 512 blocks = 2/CU
      S, WT, PZ, 256, 256, 64, 7, 256, 2, 0, 32, 16384, 0);
  reduce_relu_kernel<<<4096, 256, 0, stream>>>(PZ, C2, 1048576, 2, 1);

  wsplit_kernel<<<dim3(4, 8, 9), 256, 0, stream>>>(w_c3, WT, 256, 512, 9);
  conv_mfma<<<dim3(32, 4, 4), 256, 0, stream>>>(    // Z=4: 512 blocks = 2/CU
      C2, WT, PZ, 128, 128, 256, 6, 512, 2, 0, 64, 4096, 0);
  reduce_relu_kernel<<<2048, 256, 0, stream>>>(PZ, C3, 524288, 4, 1);

  wsplit_kernel<<<dim3(8, 16, 9), 256, 0, stream>>>(w_c4, WT, 512, 1024, 9);
  conv_mfma<<<dim3(8, 8, 8), 256, 0, stream>>>(
      C3, WT, S, 64, 64, 512, 5, 1024, 2, 0, 64, 1024, 0);
  reduce_relu_kernel<<<1024, 256, 0, stream>>>(S, C4, 262144, 8, 1);

  wsplit_kernel<<<dim3(16, 32, 9), 256, 0, stream>>>(w_c5, WT, 1024, 2048, 9);
  conv_mfma<<<dim3(2, 16, 16), 256, 0, stream>>>(
      C4, WT, S, 32, 32, 1024, 4, 2048, 2, 0, 64, 256, 0);
  reduce_relu_kernel<<<512, 256, 0, stream>>>(S, C5, 131072, 16, 1);

  // FPN laterals: gemm64 + Z-reduce with fused up2 add
  gemm64<<<dim3(4, 4, 8), 256, 0, stream>>>(C5, l5, S, 2048, 256, 256, 256);
  reduce_up2_kernel<<<64, 256, 0, stream>>>(S, nullptr, P5, 16384, 8, 4);
  gemm64<<<dim3(16, 4, 4), 256, 0, stream>>>(C4, l4, S, 1024, 256, 256, 1024);
  reduce_up2_kernel<<<256, 256, 0, stream>>>(S, P5, P4, 65536, 4, 5);
  gemm64<<<dim3(64, 4, 2), 256, 0, stream>>>(C3, l3, S, 512, 256, 256, 4096);
  reduce_up2_kernel<<<1024, 256, 0, stream>>>(S, P4, P3P, 262144, 2, 6);

  // o3 conv (no relu)
  wsplit_kernel<<<dim3(4, 4, 9), 256, 0, stream>>>(o3w, WT, 256, 256, 9);
  conv_mfma<<<dim3(32, 2, 8), 256, 0, stream>>>(
      P3P, WT, S, 64, 64, 256, 6, 256, 1, 1, 32, 4096, 0);
  reduce_relu_kernel<<<1024, 256, 0, stream>>>(S, P3, 262144, 8, 0);

  // rpn shared conv (relu)
  wsplit_kernel<<<dim3(4, 4, 9), 256, 0, stream>>>(w_rpn, WT, 256, 256, 9);
  conv_mfma<<<dim3(32, 2, 8), 256, 0, stream>>>(
      P3, WT, S, 64, 64, 256, 6, 256, 1, 1, 32, 4096, 0);
  reduce_relu_kernel<<<1024, 256, 0, stream>>>(S, T, 262144, 8, 1);

  // obj head + sigmoid, then NMS
  obj_sigmoid_kernel<<<64, 256, 0, stream>>>(T, w_obj, SC);
  nms_kernel<<<1, 1024, 0, stream>>>(SC, out);
}

// Round 4
// 619.927 us; speedup vs baseline: 1.0716x; 1.0716x over previous
//
#include <hip/hip_runtime.h>
#include <hip/hip_bf16.h>

typedef float f4 __attribute__((ext_vector_type(4)));
typedef short s8v __attribute__((ext_vector_type(8)));      // 8 bf16 (MFMA frag)
typedef unsigned short us4 __attribute__((ext_vector_type(4)));
typedef unsigned short us8 __attribute__((ext_vector_type(8)));

#define AP 40  // LDS row pad: 40 ushorts = 80 B = 20 banks -> 2-way (free)

// ---------------------------------------------------------------------------
// Stem: 512x512x3 --7x7 s2 pad2--> 256x256x64, ReLU. (fp32, small)
// ---------------------------------------------------------------------------
__global__ __launch_bounds__(256) void stem_kernel(
    const float* __restrict__ in, const float* __restrict__ w,
    float* __restrict__ out)
{
  __shared__ float in_lds[37 * 37 * 3];
  __shared__ float w_lds[7 * 7 * 3 * 64];
  const int tid = threadIdx.x;
  const int ty0 = (blockIdx.x >> 4) * 16;
  const int tx0 = (blockIdx.x & 15) * 16;

  for (int idx = tid; idx < 9408; idx += 256) w_lds[idx] = w[idx];
  for (int idx = tid; idx < 4107; idx += 256) {
    int ci = idx % 3;
    int rem = idx / 3;
    int ix = rem % 37, iy = rem / 37;
    int gy = ty0 * 2 - 2 + iy, gx = tx0 * 2 - 2 + ix;
    float v = 0.f;
    if ((unsigned)gy < 512u && (unsigned)gx < 512u)
      v = in[(gy * 512 + gx) * 3 + ci];
    in_lds[idx] = v;
  }
  __syncthreads();

  const int co = (tid & 15) * 4;
  const int py = tid >> 4;
  f4 acc[16];
#pragma unroll
  for (int px = 0; px < 16; ++px) acc[px] = (f4)0.f;

  for (int ky = 0; ky < 7; ++ky)
    for (int kx = 0; kx < 7; ++kx)
#pragma unroll
      for (int ci = 0; ci < 3; ++ci) {
        f4 wv = *(const f4*)&w_lds[(((ky * 7 + kx) * 3) + ci) * 64 + co];
        const float* ip = &in_lds[((2 * py + ky) * 37 + kx) * 3 + ci];
#pragma unroll
        for (int px = 0; px < 16; ++px) {
          float iv = ip[px * 6];
          acc[px] += iv * wv;
        }
      }

#pragma unroll
  for (int px = 0; px < 16; ++px) {
    int oy = ty0 + py, ox = tx0 + px;
    f4 o = acc[px];
#pragma unroll
    for (int c = 0; c < 4; ++c) o[c] = fmaxf(o[c], 0.f);
    *(f4*)&out[(oy * 256 + ox) * 64 + co] = o;
  }
}

// ---------------------------------------------------------------------------
// Weight prep: fp32 [tap][ci][co] -> 3-term bf16 split, TRANSPOSED to
// [L][tap][co][ci] (ushort).
// ---------------------------------------------------------------------------
__global__ __launch_bounds__(256) void wsplit_kernel(
    const float* __restrict__ w, unsigned short* __restrict__ wt,
    int C_in, int C_out, int taps)
{
  __shared__ float t[64][68];
  const int tid = threadIdx.x;
  const int tap = blockIdx.z;
  const int ci0 = blockIdx.x * 64;
  const int co0 = blockIdx.y * 64;
  const size_t lstride = (size_t)taps * C_in * C_out;

#pragma unroll
  for (int q = 0; q < 4; ++q) {
    int f = q * 256 + tid;
    int r = f >> 4, c = f & 15;  // r = ci row, c = co f4-col
    f4 v = *(const f4*)&w[((size_t)(tap * C_in + ci0 + r)) * C_out + co0 + c * 4];
    *(f4*)&t[r][c * 4] = v;
  }
  __syncthreads();

#pragma unroll
  for (int q = 0; q < 4; ++q) {
    int f = q * 256 + tid;
    int r = f >> 4, c = f & 15;  // r = co row, c = ci f4-col
    us4 h, m, l;
#pragma unroll
    for (int u = 0; u < 4; ++u) {
      float s = t[c * 4 + u][r];
      unsigned int ub = __float_as_uint(s);
      unsigned short hh = (unsigned short)(ub >> 16);
      float r1 = s - __uint_as_float((unsigned int)hh << 16);
      unsigned short mm = (unsigned short)(__float_as_uint(r1) >> 16);
      float r2 = r1 - __uint_as_float((unsigned int)mm << 16);
      unsigned short ll = (unsigned short)(__float_as_uint(r2) >> 16);
      h[u] = hh; m[u] = mm; l[u] = ll;
    }
    size_t base = ((size_t)tap * C_out + co0 + r) * C_in + ci0 + c * 4;
    *(us4*)&wt[base] = h;
    *(us4*)&wt[lstride + base] = m;
    *(us4*)&wt[2 * lstride + base] = l;
  }
}

// ---------------------------------------------------------------------------
// 3x3 conv via MFMA (16x16x32 bf16) with exact 3-term split (6 products).
// Tile 128 pix x 128 co, 4 waves, chunk K=32. LDS rows padded to AP=40.
// R10: register-pipelined staging + bijective XCD swizzle (validated).
// ---------------------------------------------------------------------------
__global__ __launch_bounds__(256, 2) void conv_mfma(
    const float* __restrict__ in, const unsigned short* __restrict__ wt,
    float* __restrict__ pout,
    int H_in, int W_in, int C_in, int wshift, int C_out,
    int stride, int pad, int ci_per_z, int npix, int relu)
{
  __shared__ __align__(16) unsigned short At[3][128][AP];
  __shared__ __align__(16) unsigned short Bt[3][128][AP];  // [L][co][k]
  const int tid = threadIdx.x;

  // XCD-aware bijective swizzle: HW round-robins flat block id across 8 XCDs;
  // remap so XCD x gets contiguous work [x*nwg/8, (x+1)*nwg/8).
  const int nwg = gridDim.x * gridDim.y * gridDim.z;
  const int hwid = blockIdx.x + gridDim.x * (blockIdx.y + gridDim.y * blockIdx.z);
  const int wid = ((nwg & 7) == 0) ? (hwid & 7) * (nwg >> 3) + (hwid >> 3) : hwid;
  const int bx = wid % gridDim.x;
  const int brem = wid / gridDim.x;
  const int by = brem % gridDim.y;
  const int bz = brem / gridDim.y;

  const int pix_base = bx * 128;
  const int co_base = by * 128;
  const int ci_z0 = bz * ci_per_z;
  const int wmask = (1 << wshift) - 1;
  const size_t lstride = (size_t)9 * C_in * C_out;

  const int lane = tid & 63, wv = tid >> 6;
  const int pixhalf = (wv >> 1) * 64, cohalf = (wv & 1) * 64;
  const int fm = lane & 15, fq = lane >> 4;

  int a_pix[4], a_c4[4], a_ys[4], a_xs[4];
#pragma unroll
  for (int q = 0; q < 4; ++q) {
    int f = q * 256 + tid;
    a_pix[q] = f >> 3; a_c4[q] = f & 7;
    int p = pix_base + a_pix[q];
    a_ys[q] = (p >> wshift) * stride - pad;
    a_xs[q] = (p & wmask) * stride - pad;
  }
  int b_col[2], b_seg[2];
#pragma unroll
  for (int q = 0; q < 2; ++q) {
    int f = q * 256 + tid;
    b_col[q] = f >> 2; b_seg[q] = (f & 3) * 8;
  }

  const int nc = ci_per_z >> 5;       // chunks per tap: 1 or 2
  const int ncsh = nc >> 1;           // log2(nc): 0 or 1
  const int nchunks = 9 * nc;

  f4 areg[4];
  us8 breg[6];
  auto issue_loads = [&](int c) {
    int tap = c >> ncsh;
    int ci = ci_z0 + (c & (nc - 1)) * 32;
    int ky = tap / 3, kx = tap - ky * 3;
#pragma unroll
    for (int q = 0; q < 4; ++q) {
      int iy = a_ys[q] + ky, ix = a_xs[q] + kx;
      bool v = ((unsigned)iy < (unsigned)H_in) & ((unsigned)ix < (unsigned)W_in);
      const float* p = in + (size_t)(iy * W_in + ix) * C_in + ci + a_c4[q] * 4;
      areg[q] = v ? *(const f4*)p : (f4)0.f;
    }
    const unsigned short* bb =
        wt + (size_t)tap * C_out * C_in + (size_t)co_base * C_in + ci;
#pragma unroll
    for (int L = 0; L < 3; ++L)
#pragma unroll
      for (int q = 0; q < 2; ++q)
        breg[L * 2 + q] = *(const us8*)(bb + (size_t)L * lstride +
                                        (size_t)b_col[q] * C_in + b_seg[q]);
  };

  us4 ah[4], am[4], al[4];
  auto convert = [&]() {
#pragma unroll
    for (int q = 0; q < 4; ++q) {
      f4 s4 = areg[q];
      us4 h, m, l;
#pragma unroll
      for (int u = 0; u < 4; ++u) {
        float s = s4[u];
        unsigned int ub = __float_as_uint(s);
        unsigned short hh = (unsigned short)(ub >> 16);
        float r1 = s - __uint_as_float((unsigned int)hh << 16);
        unsigned short mm = (unsigned short)(__float_as_uint(r1) >> 16);
        float r2 = r1 - __uint_as_float((unsigned int)mm << 16);
        unsigned short ll = (unsigned short)(__float_as_uint(r2) >> 16);
        h[u] = hh; m[u] = mm; l[u] = ll;
      }
      ah[q] = h; am[q] = m; al[q] = l;
    }
  };

  f4 acc[4][4];
#pragma unroll
  for (int i = 0; i < 4; ++i)
#pragma unroll
    for (int j = 0; j < 4; ++j) acc[i][j] = (f4)0.f;

  issue_loads(0);
  convert();

  for (int c = 0; c < nchunks; ++c) {
    __syncthreads();
#pragma unroll
    for (int q = 0; q < 4; ++q) {
      *(us4*)&At[0][a_pix[q]][a_c4[q] * 4] = ah[q];
      *(us4*)&At[1][a_pix[q]][a_c4[q] * 4] = am[q];
      *(us4*)&At[2][a_pix[q]][a_c4[q] * 4] = al[q];
    }
#pragma unroll
    for (int L = 0; L < 3; ++L)
#pragma unroll
      for (int q = 0; q < 2; ++q)
        *(us8*)&Bt[L][b_col[q]][b_seg[q]] = breg[L * 2 + q];
    __syncthreads();

    const bool more = (c + 1 < nchunks);
    if (more) issue_loads(c + 1);  // latency hidden under the MFMAs below

    s8v Bh[4], Bm[4], Bl[4];
#pragma unroll
    for (int j = 0; j < 4; ++j) {
      Bh[j] = *(const s8v*)&Bt[0][cohalf + j * 16 + fm][fq * 8];
      Bm[j] = *(const s8v*)&Bt[1][cohalf + j * 16 + fm][fq * 8];
      Bl[j] = *(const s8v*)&Bt[2][cohalf + j * 16 + fm][fq * 8];
    }
    {
      s8v Ah[4];
#pragma unroll
      for (int i = 0; i < 4; ++i)
        Ah[i] = *(const s8v*)&At[0][pixhalf + i * 16 + fm][fq * 8];
#pragma unroll
      for (int i = 0; i < 4; ++i)
#pragma unroll
        for (int j = 0; j < 4; ++j) {
          acc[i][j] = __builtin_amdgcn_mfma_f32_16x16x32_bf16(Ah[i], Bh[j], acc[i][j], 0, 0, 0);
          acc[i][j] = __builtin_amdgcn_mfma_f32_16x16x32_bf16(Ah[i], Bm[j], acc[i][j], 0, 0, 0);
          acc[i][j] = __builtin_amdgcn_mfma_f32_16x16x32_bf16(Ah[i], Bl[j], acc[i][j], 0, 0, 0);
        }
    }
    {
      s8v Am[4];
#pragma unroll
      for (int i = 0; i < 4; ++i)
        Am[i] = *(const s8v*)&At[1][pixhalf + i * 16 + fm][fq * 8];
#pragma unroll
      for (int i = 0; i < 4; ++i)
#pragma unroll
        for (int j = 0; j < 4; ++j) {
          acc[i][j] = __builtin_amdgcn_mfma_f32_16x16x32_bf16(Am[i], Bh[j], acc[i][j], 0, 0, 0);
          acc[i][j] = __builtin_amdgcn_mfma_f32_16x16x32_bf16(Am[i], Bm[j], acc[i][j], 0, 0, 0);
        }
    }
    {
      s8v Al[4];
#pragma unroll
      for (int i = 0; i < 4; ++i)
        Al[i] = *(const s8v*)&At[2][pixhalf + i * 16 + fm][fq * 8];
#pragma unroll
      for (int i = 0; i < 4; ++i)
#pragma unroll
        for (int j = 0; j < 4; ++j)
          acc[i][j] = __builtin_amdgcn_mfma_f32_16x16x32_bf16(Al[i], Bh[j], acc[i][j], 0, 0, 0);
    }

    if (more) convert();  // fp32->3xbf16 split of chunk c+1, in MFMA shadow
  }

  float* dst = pout + (size_t)bz * npix * C_out;
#pragma unroll
  for (int i = 0; i < 4; ++i) {
#pragma unroll
    for (int j = 0; j < 4; ++j) {
#pragma unroll
      for (int r = 0; r < 4; ++r) {
        int p = pix_base + pixhalf + i * 16 + fq * 4 + r;
        int co = co_base + cohalf + j * 16 + fm;
        float v = acc[i][j][r];
        if (relu) v = fmaxf(v, 0.f);
        dst[(size_t)p * C_out + co] = v;
      }
    }
  }
}

// ---------------------------------------------------------------------------
// Sum Z partial slices (f4-vectorized) + optional ReLU.
// ---------------------------------------------------------------------------
__global__ __launch_bounds__(256) void reduce_relu_kernel(
    const float* __restrict__ p, float* __restrict__ out, int n4, int Z, int relu)
{
  int idx = blockIdx.x * 256 + threadIdx.x;
  if (idx >= n4) return;
  const f4* pv = (const f4*)p;
  f4 s = pv[idx];
  for (int z = 1; z < Z; ++z) s += pv[(size_t)z * n4 + idx];
  if (relu) {
#pragma unroll
    for (int c = 0; c < 4; ++c) s[c] = fmaxf(s[c], 0.f);
  }
  ((f4*)out)[idx] = s;
}

// ---------------------------------------------------------------------------
// 1x1-conv GEMM tile: 64 pix x 64 co, 256 thr, 4 pix x 4 co per thread.
// ---------------------------------------------------------------------------
__global__ __launch_bounds__(256) void gemm64(
    const float* __restrict__ in, const float* __restrict__ w,
    float* __restrict__ pout, int C_in, int C_out, int ci_per_z, int npix)
{
  __shared__ __align__(16) float As2[32][68];
  __shared__ __align__(16) float Bs[32][64];
  const int tid = threadIdx.x;
  const int pix_base = blockIdx.x * 64;
  const int co_base = blockIdx.y * 64;
  const int ci_z0 = blockIdx.z * ci_per_z;
  const int tx = tid & 15, ty = tid >> 4;

  int ga_pix[2], ga_c4[2];
#pragma unroll
  for (int q = 0; q < 2; ++q) {
    int f = q * 256 + tid;
    ga_pix[q] = f >> 3; ga_c4[q] = f & 7;
  }
  int gb_row[2], gb_c4[2];
#pragma unroll
  for (int q = 0; q < 2; ++q) {
    int f = q * 256 + tid;
    gb_row[q] = f >> 4; gb_c4[q] = f & 15;
  }

  f4 acc[4];
#pragma unroll
  for (int i = 0; i < 4; ++i) acc[i] = (f4)0.f;

  for (int ci = ci_z0; ci < ci_z0 + ci_per_z; ci += 32) {
    __syncthreads();
#pragma unroll
    for (int q = 0; q < 2; ++q) {
      f4 av = *(const f4*)&in[(size_t)(pix_base + ga_pix[q]) * C_in + ci + ga_c4[q] * 4];
#pragma unroll
      for (int u = 0; u < 4; ++u) As2[ga_c4[q] * 4 + u][ga_pix[q]] = av[u];
    }
#pragma unroll
    for (int q = 0; q < 2; ++q) {
      *(f4*)&Bs[gb_row[q]][gb_c4[q] * 4] =
          *(const f4*)&w[(size_t)(ci + gb_row[q]) * C_out + co_base + gb_c4[q] * 4];
    }
    __syncthreads();
#pragma unroll
    for (int kk = 0; kk < 32; ++kk) {
      f4 a = *(const f4*)&As2[kk][ty * 4];
      f4 b = *(const f4*)&Bs[kk][tx * 4];
#pragma unroll
      for (int i = 0; i < 4; ++i) acc[i] += a[i] * b;
    }
  }

  float* dst = pout + (size_t)blockIdx.z * npix * C_out;
#pragma unroll
  for (int i = 0; i < 4; ++i)
    *(f4*)&dst[(size_t)(pix_base + ty * 4 + i) * C_out + co_base + tx * 4] = acc[i];
}

// ---------------------------------------------------------------------------
// Sum Z partial slices + optional fused nearest-up2 residual (C_out=256).
// ---------------------------------------------------------------------------
__global__ __launch_bounds__(256) void reduce_up2_kernel(
    const float* __restrict__ p, const float* __restrict__ res,
    float* __restrict__ out, int n4, int Z, int wshift)
{
  int idx = blockIdx.x * 256 + threadIdx.x;
  if (idx >= n4) return;
  const f4* pv = (const f4*)p;
  f4 s = pv[idx];
  for (int z = 1; z < Z; ++z) s += pv[(size_t)z * n4 + idx];
  if (res) {
    int pix = idx >> 6, c4 = idx & 63;
    int oy = pix >> wshift, ox = pix & ((1 << wshift) - 1);
    int rp = ((oy >> 1) << (wshift - 1)) + (ox >> 1);
    s += ((const f4*)res)[rp * 64 + c4];
  }
  ((f4*)out)[idx] = s;
}

// ---------------------------------------------------------------------------
// obj head (1x1, 256->1) + sigmoid. 4 threads/pixel, quad shuffle-reduce.
// ---------------------------------------------------------------------------
__global__ __launch_bounds__(256) void obj_sigmoid_kernel(
    const float* __restrict__ t, const float* __restrict__ wobj,
    float* __restrict__ scores)
{
  __shared__ float wl[256];
  const int tid = threadIdx.x;
  wl[tid] = wobj[tid];
  __syncthreads();
  const int pix = blockIdx.x * 64 + (tid >> 2);
  const int c0 = (tid & 3) * 64;
  float acc = 0.f;
#pragma unroll
  for (int k = 0; k < 16; ++k) {
    f4 tv = *(const f4*)&t[(size_t)pix * 256 + c0 + k * 4];
    const float* wp = &wl[c0 + k * 4];
    acc += tv[0] * wp[0] + tv[1] * wp[1] + tv[2] * wp[2] + tv[3] * wp[3];
  }
  acc += __shfl_xor(acc, 1);
  acc += __shfl_xor(acc, 2);
  if ((tid & 3) == 0) scores[pix] = 1.f / (1.f + expf(-acc));
}

// ---------------------------------------------------------------------------
// NMS via sort + scan-accept.
// R11: register-resident bitonic sort (validated bit-exact).
// R12: (a) sort k-rounds fully unrolled -> shfl masks become compile-time
//      constants (ds_swizzle), no per-stage loop overhead.
//      (b) greedy pre-scan parallelized over all 16 waves: wave w checks each
//      lane's candidate vs accepted {w, w+16, ...}, per-wave ballot -> LDS,
//      wave 0 ORs the 16 masks. Accept loop (inherently serial) unchanged in
//      wave 0. Same IoU arithmetic, same order, OR is order-independent ->
//      bit-identical output. Was: single wave scanning n<=100 accepted per
//      batch with dependent LDS reads = the real 40+ us cost.
// ---------------------------------------------------------------------------
__global__ __launch_bounds__(1024) void nms_kernel(
    const float* __restrict__ scores, float* __restrict__ out)
{
  __shared__ unsigned long long keys[4096];  // 32 KB
  __shared__ float acc_lds[100 * 8];         // accepted: b0,b1,b2,b3,area
  __shared__ unsigned long long supm[16];    // per-wave suppression ballots
  __shared__ int n_sh;
  const int tid = threadIdx.x;
  const float inv63 = 1.0f / 63.0f;

  if (tid < 125) ((f4*)out)[tid] = (f4)0.f;

  unsigned long long kr[4];
  {
    f4 sv = ((const f4*)scores)[tid];
#pragma unroll
    for (int v = 0; v < 4; ++v) {
      unsigned int bits = __float_as_uint(sv[v]);  // in [0, 0x3F800000]
      kr[v] = ((unsigned long long)(0x40000000u - bits) << 16) |
              (unsigned long long)(tid * 4 + v);
    }
  }

#pragma unroll
  for (int kb = 1; kb <= 12; ++kb) {
    const int k = 1 << kb;
    // --- cross-wave stages (j >= 256) via LDS ---
#pragma unroll
    for (int j = k >> 1; j >= 256; j >>= 1) {
      *(ulonglong2*)&keys[tid * 4] = ulonglong2{kr[0], kr[1]};
      *(ulonglong2*)&keys[tid * 4 + 2] = ulonglong2{kr[2], kr[3]};
      __syncthreads();
      ulonglong2 p0 = *(const ulonglong2*)&keys[(tid * 4) ^ j];
      ulonglong2 p1 = *(const ulonglong2*)&keys[((tid * 4) ^ j) + 2];
      unsigned long long pb[4] = {p0.x, p0.y, p1.x, p1.y};
#pragma unroll
      for (int v = 0; v < 4; ++v) {
        int e = tid * 4 + v;
        bool up = ((e & k) == 0);
        bool lower = ((e & j) == 0);
        bool keep_min = (lower == up);
        unsigned long long a = kr[v], b = pb[v];
        unsigned long long mn = a < b ? a : b;
        unsigned long long mx = a < b ? b : a;
        kr[v] = keep_min ? mn : mx;
      }
      __syncthreads();  // protect this stage's reads from next stage's writes
    }
    // --- intra-wave stages (j = 4..128) via shfl_xor (constant masks) ---
    {
      const int js = (k >> 1) < 128 ? (k >> 1) : 128;
#pragma unroll
      for (int j = js; j >= 4; j >>= 1) {
        const int lm = j >> 2;  // lane xor mask (1..32)
        bool lower = ((tid & lm) == 0);
        bool up = ((tid & (k >> 2)) == 0);  // k >= 8 here
        bool keep_min = (lower == up);
#pragma unroll
        for (int v = 0; v < 4; ++v) {
          unsigned long long b = __shfl_xor(kr[v], lm);
          unsigned long long a = kr[v];
          unsigned long long mn = a < b ? a : b;
          unsigned long long mx = a < b ? b : a;
          kr[v] = keep_min ? mn : mx;
        }
      }
    }
    // --- in-thread stage j = 2 (pairs (v0,v2),(v1,v3)) ---
    if (k >= 4) {
#pragma unroll
      for (int v = 0; v < 2; ++v) {
        bool up = (((tid * 4 + v) & k) == 0);
        unsigned long long a = kr[v], b = kr[v + 2];
        if ((a > b) == up) { kr[v] = b; kr[v + 2] = a; }
      }
    }
    // --- in-thread stage j = 1 (pairs (v0,v1),(v2,v3)) ---
    {
#pragma unroll
      for (int v = 0; v < 4; v += 2) {
        bool up = (((tid * 4 + v) & k) == 0);
        unsigned long long a = kr[v], b = kr[v + 1];
        if ((a > b) == up) { kr[v] = b; kr[v + 1] = a; }
      }
    }
  }

  // publish sorted keys for the greedy phase
  *(ulonglong2*)&keys[tid * 4] = ulonglong2{kr[0], kr[1]};
  *(ulonglong2*)&keys[tid * 4 + 2] = ulonglong2{kr[2], kr[3]};
  if (tid == 0) n_sh = 0;
  __syncthreads();

  const int wv = tid >> 6, lane = tid & 63;
  int n = 0;
  for (int b = 0; b < 64 && n < 100; ++b) {
    // every wave computes each lane's candidate box (cheap, uniform)
    unsigned long long kk = keys[b * 64 + lane];
    int idx = (int)(kk & 0xFFFF);
    int si = idx >> 6, sj = idx & 63;
    float y = sj * inv63, x = si * inv63;
    float c0 = fmaxf(y - 0.05f, 0.f), c1 = fmaxf(x - 0.05f, 0.f);
    float c2 = fminf(y + 0.05f, 1.f), c3 = fminf(x + 0.05f, 1.f);
    float carea = (c2 - c0) * (c3 - c1);

    // parallel pre-scan: wave wv checks accepted a = wv, wv+16, ...
    bool sup = false;
    for (int a = wv; a < n; a += 16) {
      f4 ab = *(const f4*)&acc_lds[a * 8];
      float aarea = acc_lds[a * 8 + 4];
      float yy1 = fmaxf(ab[0], c0), xx1 = fmaxf(ab[1], c1);
      float yy2 = fminf(ab[2], c2), xx2 = fminf(ab[3], c3);
      float inter = fmaxf(yy2 - yy1, 0.f) * fmaxf(xx2 - xx1, 0.f);
      float iou = inter / (aarea + carea - inter + 1e-9f);
      sup = sup || (iou > 0.5f);
    }
    supm[wv] = __ballot(sup);
    __syncthreads();

    if (wv == 0) {
      unsigned long long ms = supm[0];
#pragma unroll
      for (int w = 1; w < 16; ++w) ms |= supm[w];
      bool sup0 = (ms >> lane) & 1ull;
      float sc = __uint_as_float(0x40000000u - (unsigned int)(kk >> 16));
      int nn = n;
      unsigned long long m = __ballot(!sup0);
      while (m != 0 && nn < 100) {
        int u = __builtin_ctzll(m);
        float b0 = __shfl(c0, u), b1 = __shfl(c1, u);
        float b2 = __shfl(c2, u), b3 = __shfl(c3, u);
        float ba = __shfl(carea, u);
        if (lane == u) {
          acc_lds[nn * 8 + 0] = c0; acc_lds[nn * 8 + 1] = c1;
          acc_lds[nn * 8 + 2] = c2; acc_lds[nn * 8 + 3] = c3;
          acc_lds[nn * 8 + 4] = carea;
          out[nn * 4 + 0] = c0; out[nn * 4 + 1] = c1;
          out[nn * 4 + 2] = c2; out[nn * 4 + 3] = c3;
          out[400 + nn] = sc;
          sup0 = true;
        }
        nn++;
        if (lane > u && !sup0) {
          float yy1 = fmaxf(b0, c0), xx1 = fmaxf(b1, c1);
          float yy2 = fminf(b2, c2), xx2 = fminf(b3, c3);
          float inter = fmaxf(yy2 - yy1, 0.f) * fmaxf(xx2 - xx1, 0.f);
          float iou = inter / (ba + carea - inter + 1e-9f);
          if (iou > 0.5f) sup0 = true;
        }
        m = __ballot(!sup0);
      }
      if (lane == 0) n_sh = nn;
    }
    __syncthreads();
    n = n_sh;
  }
}

// ---------------------------------------------------------------------------
extern "C" void kernel_launch(void* const* d_in, const int* in_sizes, int n_in,
                              void* d_out, int out_size, void* d_ws, size_t ws_size,
                              hipStream_t stream) {
  const float* x      = (const float*)d_in[0];
  const float* w_stem = (const float*)d_in[1];
  const float* w_c2   = (const float*)d_in[2];
  const float* w_c3   = (const float*)d_in[3];
  const float* w_c4   = (const float*)d_in[4];
  const float* w_c5   = (const float*)d_in[5];
  const float* l3     = (const float*)d_in[6];
  const float* l4     = (const float*)d_in[7];
  const float* l5     = (const float*)d_in[8];
  const float* o3w    = (const float*)d_in[9];
  const float* w_rpn  = (const float*)d_in[12];
  const float* w_obj  = (const float*)d_in[13];
  float* out = (float*)d_out;
  float* ws = (float*)d_ws;

  float* S   = ws;              // 4,194,304 floats (partial scratch for c4/c5/o3/rpn)
  float* C2  = S   + 4194304;   // 4,194,304
  float* C3  = C2  + 4194304;   // 2,097,152
  float* C4  = C3  + 2097152;   // 1,048,576
  float* C5  = C4  + 1048576;   //   524,288
  float* P5  = C5  + 524288;    //    65,536
  float* P4  = P5  + 65536;     //   262,144
  float* P3P = P4  + 262144;    // 1,048,576
  float* P3  = P3P + 1048576;   // 1,048,576
  float* T   = P3  + 1048576;   // 1,048,576
  float* SC  = T   + 1048576;   //     4,096
  unsigned short* WT = (unsigned short*)(SC + 4096);  // 113.25 MB weight split
  // PZ: 33.5 MB partial scratch for c2/c3, carved at WT+60 MB. Safe: c2/c3
  // weight splits are 1.7/7.1 MB (< 60 MB); c4's 28.3 MB < 60 MB; c5's full
  // 113 MB rewrite happens only after c3 is consumed (stream-serial).
  float* PZ = (float*)(WT + 31457280);

  // backbone
  stem_kernel<<<256, 256, 0, stream>>>(x, w_stem, S);

  wsplit_kernel<<<dim3(1, 4, 9), 256, 0, stream>>>(w_c2, WT, 64, 256, 9);
  conv_mfma<<<dim3(128, 2, 2), 256, 0, stream>>>(   // Z=2: 512 blocks = 2/CU
      S, WT, PZ, 256, 256, 64, 7, 256, 2, 0, 32, 16384, 0);
  reduce_relu_kernel<<<4096, 256, 0, stream>>>(PZ, C2, 1048576, 2, 1);

  wsplit_kernel<<<dim3(4, 8, 9), 256, 0, stream>>>(w_c3, WT, 256, 512, 9);
  conv_mfma<<<dim3(32, 4, 4), 256, 0, stream>>>(    // Z=4: 512 blocks = 2/CU
      C2, WT, PZ, 128, 128, 256, 6, 512, 2, 0, 64, 4096, 0);
  reduce_relu_kernel<<<2048, 256, 0, stream>>>(PZ, C3, 524288, 4, 1);

  wsplit_kernel<<<dim3(8, 16, 9), 256, 0, stream>>>(w_c4, WT, 512, 1024, 9);
  conv_mfma<<<dim3(8, 8, 8), 256, 0, stream>>>(
      C3, WT, S, 64, 64, 512, 5, 1024, 2, 0, 64, 1024, 0);
  reduce_relu_kernel<<<1024, 256, 0, stream>>>(S, C4, 262144, 8, 1);

  wsplit_kernel<<<dim3(16, 32, 9), 256, 0, stream>>>(w_c5, WT, 1024, 2048, 9);
  conv_mfma<<<dim3(2, 16, 16), 256, 0, stream>>>(
      C4, WT, S, 32, 32, 1024, 4, 2048, 2, 0, 64, 256, 0);
  reduce_relu_kernel<<<512, 256, 0, stream>>>(S, C5, 131072, 16, 1);

  // FPN laterals: gemm64 + Z-reduce with fused up2 add
  gemm64<<<dim3(4, 4, 8), 256, 0, stream>>>(C5, l5, S, 2048, 256, 256, 256);
  reduce_up2_kernel<<<64, 256, 0, stream>>>(S, nullptr, P5, 16384, 8, 4);
  gemm64<<<dim3(16, 4, 4), 256, 0, stream>>>(C4, l4, S, 1024, 256, 256, 1024);
  reduce_up2_kernel<<<256, 256, 0, stream>>>(S, P5, P4, 65536, 4, 5);
  gemm64<<<dim3(64, 4, 2), 256, 0, stream>>>(C3, l3, S, 512, 256, 256, 4096);
  reduce_up2_kernel<<<1024, 256, 0, stream>>>(S, P4, P3P, 262144, 2, 6);

  // o3 conv (no relu)
  wsplit_kernel<<<dim3(4, 4, 9), 256, 0, stream>>>(o3w, WT, 256, 256, 9);
  conv_mfma<<<dim3(32, 2, 8), 256, 0, stream>>>(
      P3P, WT, S, 64, 64, 256, 6, 256, 1, 1, 32, 4096, 0);
  reduce_relu_kernel<<<1024, 256, 0, stream>>>(S, P3, 262144, 8, 0);

  // rpn shared conv (relu)
  wsplit_kernel<<<dim3(4, 4, 9), 256, 0, stream>>>(w_rpn, WT, 256, 256, 9);
  conv_mfma<<<dim3(32, 2, 8), 256, 0, stream>>>(
      P3, WT, S, 64, 64, 256, 6, 256, 1, 1, 32, 4096, 0);
  reduce_relu_kernel<<<1024, 256, 0, stream>>>(S, T, 262144, 8, 1);

  // obj head + sigmoid, then NMS
  obj_sigmoid_kernel<<<64, 256, 0, stream>>>(T, w_obj, SC);
  nms_kernel<<<1, 1024, 0, stream>>>(SC, out);
}